// Round 1
// baseline (70189.417 us; speedup 1.0000x reference)
//
#include <hip/hip_runtime.h>
#include <math.h>

// ---------------------------------------------------------------------------
// LSTM stack (16 layers, H=512, T=4096) + MLP head, fp32.
//
// Strategy:
//  - Two cooperative "pass" kernels (encoder 8 layers, decoder 8 layers).
//  - Each pass: 256 blocks = 8 layers x 32 blocks/layer, 512 thr/block.
//  - Per block: 64 gate rows (16 h-indices x 4 gates) of Wih|Whh held in
//    VGPRs (128 floats/thread). Recurrence runs as a per-step matvec from
//    LDS-staged [x_t | h_{t-1}] vector.
//  - Layers are pipelined: layer l step t waits on (a) its own layer's step
//    t-1 completion, (b) layer l-1's step t completion, via per-(layer,step)
//    counters with agent-scope release/acquire. All cross-CU data moves via
//    agent-scope (device-coherent) loads/stores -> cross-XCD safe.
//  - Sequence buffers S[0..7] (T x 512 each) in d_ws double as both the h
//    broadcast medium and the next layer's input.
//  - Decoder pass reads S[7] (encoder out) while its own layer 7 overwrites
//    S[7] trailing 7 steps behind; the flag chain guarantees read(t) happens
//    strictly before write(t). Safe.
// ---------------------------------------------------------------------------

#define T_SEQ   4096
#define HDIM    512
#define G4      2048      // 4*H
#define NL      8         // layers per pass
#define BPL     32        // blocks per layer
#define NTH     512       // threads per block
#define CHUNK   32        // k-floats per thread
#define VSTRIDE 36        // padded LDS chunk stride (36/4=9 odd -> bank spread)

struct PassArgs {
  const float* in0; int inD;
  const float* Wih[NL]; const float* Whh[NL];
  const float* bih[NL]; const float* bhh[NL];
  float* S;            // base of 8 sequence buffers, each T_SEQ*HDIM floats
  unsigned int* cnt;   // this pass's counters [NL][T_SEQ]
};

__device__ __forceinline__ float aloadf(const float* p) {
  return __hip_atomic_load(p, __ATOMIC_RELAXED, __HIP_MEMORY_SCOPE_AGENT);
}
__device__ __forceinline__ void astoref(float* p, float v) {
  __hip_atomic_store(p, v, __ATOMIC_RELAXED, __HIP_MEMORY_SCOPE_AGENT);
}
__device__ __forceinline__ float sigm(float x) {
  return 1.0f / (1.0f + __expf(-x));
}

__global__ void __launch_bounds__(NTH, 2) lstm_pass_kernel(PassArgs a)
{
  const int tid   = threadIdx.x;
  const int layer = blockIdx.x >> 5;   // 0..7
  const int b     = blockIdx.x & 31;   // block within layer

  const int D = (layer == 0) ? a.inD : HDIM;
  const float* __restrict__ Wih = a.Wih[layer];
  const float* __restrict__ Whh = a.Whh[layer];
  const float* __restrict__ bih = a.bih[layer];
  const float* __restrict__ bhh = a.bhh[layer];
  const float* __restrict__ in  =
      (layer == 0) ? a.in0 : (a.S + (size_t)(layer - 1) * T_SEQ * HDIM);
  float* __restrict__ Sout = a.S + (size_t)layer * T_SEQ * HDIM;
  unsigned* cnt_own  = a.cnt + (size_t)layer * T_SEQ;
  unsigned* cnt_prev = a.cnt + (size_t)(layer - 1) * T_SEQ; // valid if layer>0

  // Thread decomposition: cs = k-chunk (32 floats of the 1024-long [x|h]
  // vector), rq = row-quad (4 of the block's 64 gate rows).
  const int cs = tid & 31;
  const int rq = tid >> 5;
  const int k0 = cs * CHUNK;   // 0..992 in concat(x[0:512], h[0:512])

  // ---- load weights into registers (held across all 4096 steps) ----
  float4 w4[4][8];
  float  bias[4];
  #pragma unroll
  for (int q = 0; q < 4; ++q) {
    const int lr  = rq * 4 + q;          // local row 0..63
    const int g   = lr >> 4;             // gate: 0=i 1=f 2=g 3=o
    const int jl  = lr & 15;             // h-index within block
    const int row = g * HDIM + b * 16 + jl;
    bias[q] = bih[row] + bhh[row];
    if (k0 < HDIM) {                     // Wih part (k in [k0, k0+32))
      if (k0 + CHUNK <= D) {
        const float4* src =
            reinterpret_cast<const float4*>(Wih + (size_t)row * D + k0);
        #pragma unroll
        for (int m = 0; m < 8; ++m) w4[q][m] = src[m];
      } else {                           // beyond layer-0's D=128: zero
        #pragma unroll
        for (int m = 0; m < 8; ++m) w4[q][m] = make_float4(0.f, 0.f, 0.f, 0.f);
      }
    } else {                             // Whh part (hk = k0-512)
      const float4* src =
          reinterpret_cast<const float4*>(Whh + (size_t)row * HDIM + (k0 - HDIM));
      #pragma unroll
      for (int m = 0; m < 8; ++m) w4[q][m] = src[m];
    }
  }

  __shared__ __align__(16) float v_lds[32 * VSTRIDE]; // [x|h] staged, padded
  __shared__ float y_lds[64];                          // gate pre-activations

  float c_state = 0.0f;   // cell state, used by tid<16

  for (int t = 0; t < T_SEQ; ++t) {
    // ---- wait for dependencies ----
    if (tid == 0) {
      if (t > 0)
        while (__hip_atomic_load(&cnt_own[t - 1], __ATOMIC_ACQUIRE,
                                 __HIP_MEMORY_SCOPE_AGENT) < (unsigned)BPL)
          __builtin_amdgcn_s_sleep(2);
      if (layer > 0)
        while (__hip_atomic_load(&cnt_prev[t], __ATOMIC_ACQUIRE,
                                 __HIP_MEMORY_SCOPE_AGENT) < (unsigned)BPL)
          __builtin_amdgcn_s_sleep(2);
    }
    __syncthreads();

    // ---- stage x_t and h_{t-1} into LDS (device-coherent loads) ----
    const float xv = (tid < D) ? aloadf(in + (size_t)t * D + tid) : 0.0f;
    const float hv = (t > 0) ? aloadf(Sout + (size_t)(t - 1) * HDIM + tid) : 0.0f;
    v_lds[(tid >> 5) * VSTRIDE + (tid & 31)] = xv;                 // k = tid
    v_lds[((tid + HDIM) >> 5) * VSTRIDE + (tid & 31)] = hv;        // k = 512+tid
    __syncthreads();

    // ---- matvec: 4 rows x 32 k per thread ----
    float acc0 = 0.f, acc1 = 0.f, acc2 = 0.f, acc3 = 0.f;
    const float4* v4 = reinterpret_cast<const float4*>(v_lds) + cs * 9;
    #pragma unroll
    for (int m = 0; m < 8; ++m) {
      const float4 vv = v4[m];
      acc0 = fmaf(w4[0][m].x, vv.x, acc0); acc0 = fmaf(w4[0][m].y, vv.y, acc0);
      acc0 = fmaf(w4[0][m].z, vv.z, acc0); acc0 = fmaf(w4[0][m].w, vv.w, acc0);
      acc1 = fmaf(w4[1][m].x, vv.x, acc1); acc1 = fmaf(w4[1][m].y, vv.y, acc1);
      acc1 = fmaf(w4[1][m].z, vv.z, acc1); acc1 = fmaf(w4[1][m].w, vv.w, acc1);
      acc2 = fmaf(w4[2][m].x, vv.x, acc2); acc2 = fmaf(w4[2][m].y, vv.y, acc2);
      acc2 = fmaf(w4[2][m].z, vv.z, acc2); acc2 = fmaf(w4[2][m].w, vv.w, acc2);
      acc3 = fmaf(w4[3][m].x, vv.x, acc3); acc3 = fmaf(w4[3][m].y, vv.y, acc3);
      acc3 = fmaf(w4[3][m].z, vv.z, acc3); acc3 = fmaf(w4[3][m].w, vv.w, acc3);
    }
    // reduce across the 32 cs-lanes (stays within each 32-lane half)
    #pragma unroll
    for (int d = 1; d < 32; d <<= 1) {
      acc0 += __shfl_xor(acc0, d);
      acc1 += __shfl_xor(acc1, d);
      acc2 += __shfl_xor(acc2, d);
      acc3 += __shfl_xor(acc3, d);
    }
    if (cs == 0) {
      y_lds[rq * 4 + 0] = acc0 + bias[0];
      y_lds[rq * 4 + 1] = acc1 + bias[1];
      y_lds[rq * 4 + 2] = acc2 + bias[2];
      y_lds[rq * 4 + 3] = acc3 + bias[3];
    }
    __syncthreads();

    // ---- gates + state update (16 h-values per block) ----
    if (tid < 16) {
      const float gi = sigm(y_lds[tid]);
      const float gf = sigm(y_lds[16 + tid]);
      const float gg = tanhf(y_lds[32 + tid]);
      const float go = sigm(y_lds[48 + tid]);
      c_state = gf * c_state + gi * gg;
      const float h = go * tanhf(c_state);
      astoref(Sout + (size_t)t * HDIM + b * 16 + tid, h);
    }
    __syncthreads();   // drains the h stores (vmcnt(0) before s_barrier)
    if (tid == 0)
      __hip_atomic_fetch_add(&cnt_own[t], 1u, __ATOMIC_RELEASE,
                             __HIP_MEMORY_SCOPE_AGENT);
  }
}

// ---------------- MLP head: (T,512) -> 64 -> 32 -> 16 ----------------
__global__ void __launch_bounds__(64) mlp_head_kernel(
    const float* __restrict__ S7,
    const float* __restrict__ w1, const float* __restrict__ b1,
    const float* __restrict__ w2, const float* __restrict__ b2,
    const float* __restrict__ w3, const float* __restrict__ b3,
    float* __restrict__ out)
{
  const int r   = blockIdx.x;
  const int tid = threadIdx.x;
  __shared__ float hbuf[HDIM];
  __shared__ float a1[64];
  __shared__ float a2[32];

  #pragma unroll
  for (int u = 0; u < HDIM / 64; ++u)
    hbuf[u * 64 + tid] = aloadf(S7 + (size_t)r * HDIM + u * 64 + tid);
  __syncthreads();

  float acc = b1[tid];
  #pragma unroll 8
  for (int k = 0; k < HDIM; ++k) acc = fmaf(hbuf[k], w1[tid * HDIM + k], acc);
  a1[tid] = acc * sigm(acc);          // SiLU
  __syncthreads();

  if (tid < 32) {
    float acc2 = b2[tid];
    #pragma unroll
    for (int k = 0; k < 64; ++k) acc2 = fmaf(a1[k], w2[tid * 64 + k], acc2);
    a2[tid] = acc2 * sigm(acc2);      // SiLU
  }
  __syncthreads();

  if (tid < 16) {
    float acc3 = b3[tid];
    #pragma unroll
    for (int k = 0; k < 32; ++k) acc3 = fmaf(a2[k], w3[tid * 32 + k], acc3);
    out[(size_t)r * 16 + tid] = acc3;
  }
}

// ---------------------------------------------------------------------------
extern "C" void kernel_launch(void* const* d_in, const int* in_sizes, int n_in,
                              void* d_out, int out_size, void* d_ws, size_t ws_size,
                              hipStream_t stream)
{
  (void)in_sizes; (void)n_in; (void)out_size; (void)ws_size;

  const float* x     = (const float*)d_in[0];
  const float* eWih0 = (const float*)d_in[1];
  const float* eWhh0 = (const float*)d_in[2];
  const float* ebih0 = (const float*)d_in[3];
  const float* ebhh0 = (const float*)d_in[4];
  const float* eWih  = (const float*)d_in[5];
  const float* eWhh  = (const float*)d_in[6];
  const float* ebih  = (const float*)d_in[7];
  const float* ebhh  = (const float*)d_in[8];
  const float* dWih  = (const float*)d_in[9];
  const float* dWhh  = (const float*)d_in[10];
  const float* dbih  = (const float*)d_in[11];
  const float* dbhh  = (const float*)d_in[12];
  const float* fc1w  = (const float*)d_in[13];
  const float* fc1b  = (const float*)d_in[14];
  const float* fc2w  = (const float*)d_in[15];
  const float* fc2b  = (const float*)d_in[16];
  const float* fc3w  = (const float*)d_in[17];
  const float* fc3b  = (const float*)d_in[18];
  float* out = (float*)d_out;

  // workspace layout: S[8] sequence buffers (64 MB) | counters (256 KB)
  float* S = (float*)d_ws;
  unsigned* cnt =
      (unsigned*)((char*)d_ws + (size_t)NL * T_SEQ * HDIM * sizeof(float));
  hipMemsetAsync(cnt, 0, (size_t)2 * NL * T_SEQ * sizeof(unsigned), stream);

  // ---- pass 0: encoder (layer 0 has D_in=128) ----
  PassArgs p0{};
  p0.in0 = x; p0.inD = 128;
  p0.Wih[0] = eWih0; p0.Whh[0] = eWhh0; p0.bih[0] = ebih0; p0.bhh[0] = ebhh0;
  for (int l = 1; l < NL; ++l) {
    p0.Wih[l] = eWih + (size_t)(l - 1) * G4 * HDIM;
    p0.Whh[l] = eWhh + (size_t)(l - 1) * G4 * HDIM;
    p0.bih[l] = ebih + (size_t)(l - 1) * G4;
    p0.bhh[l] = ebhh + (size_t)(l - 1) * G4;
  }
  p0.S = S; p0.cnt = cnt;
  void* a0[] = { &p0 };
  hipError_t e0 = hipLaunchCooperativeKernel((const void*)lstm_pass_kernel,
                                             dim3(NL * BPL), dim3(NTH), a0, 0,
                                             stream);
  if (e0 != hipSuccess)   // fallback: 256 blocks <= 256 CUs, all co-resident
    lstm_pass_kernel<<<dim3(NL * BPL), dim3(NTH), 0, stream>>>(p0);

  // ---- pass 1: decoder (input = S[7]; its layer 7 rewrites S[7] safely) ----
  PassArgs p1{};
  p1.in0 = S + (size_t)7 * T_SEQ * HDIM; p1.inD = HDIM;
  for (int l = 0; l < NL; ++l) {
    p1.Wih[l] = dWih + (size_t)l * G4 * HDIM;
    p1.Whh[l] = dWhh + (size_t)l * G4 * HDIM;
    p1.bih[l] = dbih + (size_t)l * G4;
    p1.bhh[l] = dbhh + (size_t)l * G4;
  }
  p1.S = S; p1.cnt = cnt + (size_t)NL * T_SEQ;
  void* a1v[] = { &p1 };
  hipError_t e1 = hipLaunchCooperativeKernel((const void*)lstm_pass_kernel,
                                             dim3(NL * BPL), dim3(NTH), a1v, 0,
                                             stream);
  if (e1 != hipSuccess)
    lstm_pass_kernel<<<dim3(NL * BPL), dim3(NTH), 0, stream>>>(p1);

  // ---- MLP head on decoder output S[7] ----
  mlp_head_kernel<<<dim3(T_SEQ), dim3(64), 0, stream>>>(
      S + (size_t)7 * T_SEQ * HDIM, fc1w, fc1b, fc2w, fc2b, fc3w, fc3b, out);
}

// Round 2
// 12216.043 us; speedup vs baseline: 5.7457x; 5.7457x over previous
//
#include <hip/hip_runtime.h>
#include <math.h>

// ---------------------------------------------------------------------------
// Fused 16-layer LSTM pipeline (H=512, T=4096) + MLP head, fp32.
//
//  - ONE cooperative kernel: 256 blocks = 16 layers x 16 blocks/layer,
//    512 threads each (1 block/CU, 8 waves). Critical chain = T+15 links
//    (vs 2*(T+7) for the two-pass version).
//  - Per block: 128 gate rows (32 h-indices x 4 gates). Per thread: 4 rows
//    (one per gate, same h-index) x 64-float K-chunk = 256 weights:
//    gates i,f,g in VGPRs (192 regs), gate o in LDS (128 KB, conflict-free
//    [m*512+tid] layout).
//  - Sync protocol: relaxed agent-scope (sc1/IF$) ops only. Each block posts
//    a monotonic per-block flag = steps completed. Consumers poll 48 flag
//    words (own layer >= t, prev layer >= t+1, next layer >= t-63 for ring
//    backpressure) with relaxed loads on wave 0 only -> no buffer_inv/wbl2,
//    no atomic-RMW serialization. h stores are drained by __syncthreads()
//    (vmcnt(0) before s_barrier) before the flag store.
//  - h/x hand-off: per-layer 64-slot ring (layers 0..14); layer 15 writes
//    the full (T,512) buffer consumed by the MLP head.
// ---------------------------------------------------------------------------

#define T_SEQ 4096
#define HDIM  512
#define NL    16
#define BPL   16      // blocks per layer
#define NTH   512
#define RING  64      // ring slots, layers 0..14
#define RMASK 63
#define FPAD  16      // flag padding (u32) -> 64B per flag word

struct Args {
  const float* x;
  const float* Wih[NL]; const float* Whh[NL];
  const float* bih[NL]; const float* bhh[NL];
  float* ring;      // [15][RING][HDIM]
  float* sout;      // [T_SEQ][HDIM]
  unsigned* flags;  // [NL*BPL*FPAD]
};

__device__ __forceinline__ float aloadf(const float* p) {
  return __hip_atomic_load(p, __ATOMIC_RELAXED, __HIP_MEMORY_SCOPE_AGENT);
}
__device__ __forceinline__ void astoref(float* p, float v) {
  __hip_atomic_store(p, v, __ATOMIC_RELAXED, __HIP_MEMORY_SCOPE_AGENT);
}
__device__ __forceinline__ unsigned aloadu(const unsigned* p) {
  return __hip_atomic_load(p, __ATOMIC_RELAXED, __HIP_MEMORY_SCOPE_AGENT);
}
__device__ __forceinline__ float sigm(float x) { return 1.0f / (1.0f + __expf(-x)); }

#define DOT4(acc, wv, vv)                \
  acc = fmaf((wv).x, (vv).x, acc);       \
  acc = fmaf((wv).y, (vv).y, acc);       \
  acc = fmaf((wv).z, (vv).z, acc);       \
  acc = fmaf((wv).w, (vv).w, acc)

__global__ void __launch_bounds__(NTH, 2) lstm16_kernel(Args a)
{
  const int tid   = threadIdx.x;
  const int layer = blockIdx.x & 15;   // 0..15 (0..7 enc, 8..15 dec)
  const int b     = blockIdx.x >> 4;   // 0..15 block within layer
  const int cs    = tid & 15;          // K-chunk (64 floats each)
  const int rr    = tid >> 4;          // h-index within block's 32
  const int k0    = cs * 64;           // start in concat [x(512) | h(512)]
  const int D     = layer ? HDIM : 128;

  __shared__ __align__(16) float4 wl[16 * NTH];  // o-gate weights, 128 KB
  __shared__ __align__(16) float  v[1024];       // [x|h], rotation-swizzled

  const float* __restrict__ Wih = a.Wih[layer];
  const float* __restrict__ Whh = a.Whh[layer];

  // ---- load weights: q=0..2 (i,f,g) -> VGPR, q=3 (o) -> LDS ----
  float4 w[3][16];
  float  bias4[4];
  #pragma unroll
  for (int q = 0; q < 4; ++q) {
    const int row = q * HDIM + b * 32 + rr;      // global gate row (0..2047)
    bias4[q] = a.bih[layer][row] + a.bhh[layer][row];
    const float4* src = nullptr;
    if (k0 < HDIM) {
      if (k0 + 64 <= D)
        src = reinterpret_cast<const float4*>(Wih + (size_t)row * D + k0);
      // else: beyond layer-0's D=128 -> zeros
    } else {
      src = reinterpret_cast<const float4*>(Whh + (size_t)row * HDIM + (k0 - HDIM));
    }
    if (q == 3) {
      #pragma unroll
      for (int m = 0; m < 16; ++m) {
        float4 t = make_float4(0.f, 0.f, 0.f, 0.f);
        if (src) t = src[m];
        wl[m * NTH + tid] = t;                  // [m*512+tid]: b128 reads conflict-free
      }
    } else {
      #pragma unroll
      for (int m = 0; m < 16; ++m) {
        float4 t = make_float4(0.f, 0.f, 0.f, 0.f);
        if (src) t = src[m];
        w[q][m] = t;
      }
    }
  }

  // v physical indices (rotation swizzle: chunk c, float4 j -> (j+c)&15)
  const int c1 = tid >> 6, j1 = (tid >> 2) & 15;
  const int p1 = (c1 << 6) + (((j1 + c1) & 15) << 2) + (tid & 3);        // x slot
  const int c2 = 8 + (tid >> 6);
  const int p2 = (c2 << 6) + (((j1 + c2) & 15) << 2) + (tid & 3);        // h slot
  if (tid >= D) v[p1] = 0.0f;   // layer-0 unused x region, written once
  __syncthreads();

  // ---- sync setup: wave-0 lane roles for flag polling ----
  const unsigned* fptr = a.flags;  // dummy valid ptr for inactive lanes
  int role = 3;                    // 0=own(t) 1=prev(t+1) 2=next(t-63) 3=none
  if (tid < 16)       { role = 0; fptr = a.flags + (size_t)(layer * BPL + tid) * FPAD; }
  else if (tid < 32)  { if (layer > 0)  { role = 1; fptr = a.flags + (size_t)((layer - 1) * BPL + (tid - 16)) * FPAD; } }
  else if (tid < 48)  { if (layer < 15) { role = 2; fptr = a.flags + (size_t)((layer + 1) * BPL + (tid - 32)) * FPAD; } }

  float* outp = (layer == 15) ? a.sout : (a.ring + (size_t)layer * RING * HDIM);
  const float* hbase = outp;
  const int hmask = (layer == 15) ? (T_SEQ - 1) : RMASK;
  const float* xbase = layer ? (a.ring + (size_t)(layer - 1) * RING * HDIM) : a.x;
  unsigned* myflag = a.flags + (size_t)(layer * BPL + b) * FPAD;

  float c_state = 0.0f;   // owned by cs==0 threads (h-index b*32+rr)

  for (int t = 0; t < T_SEQ; ++t) {
    // ---- poll dependencies (wave 0 only, relaxed loads, no fences) ----
    if (tid < 64) {
      unsigned need = 0;
      if (role == 0)      need = (unsigned)t;
      else if (role == 1) need = (unsigned)(t + 1);
      else if (role == 2) need = (t >= RING) ? (unsigned)(t - RING + 1) : 0u;
      bool ok;
      do { ok = (role == 3) || (aloadu(fptr) >= need); } while (!__all(ok));
    }
    __syncthreads();                                   // B1: releases all waves

    // ---- fetch h_{t-1} (own layer) and x_t (prev layer / input) ----
    float hv = 0.0f;
    if (t > 0) hv = aloadf(hbase + (size_t)((t - 1) & hmask) * HDIM + tid);
    float xv = 0.0f;
    if (layer > 0)       xv = aloadf(xbase + (size_t)(t & RMASK) * HDIM + tid);
    else if (tid < 128)  xv = a.x[(size_t)t * 128 + tid];   // const input: plain load
    v[p2] = hv;
    if (tid < D) v[p1] = xv;
    __syncthreads();                                   // B2: v staged

    // ---- matvec: 4 gate rows x 64 K per thread ----
    float a0 = 0.f, a1 = 0.f, a2 = 0.f, a3 = 0.f;
    #pragma unroll
    for (int m = 0; m < 16; ++m) {
      const float4 vv = *reinterpret_cast<const float4*>(
          v + (cs << 6) + (((m + cs) & 15) << 2));     // 2-way bank alias: free
      const float4 wo = wl[m * NTH + tid];
      DOT4(a0, w[0][m], vv);
      DOT4(a1, w[1][m], vv);
      DOT4(a2, w[2][m], vv);
      DOT4(a3, wo, vv);
    }
    #pragma unroll
    for (int d = 1; d < 16; d <<= 1) {                 // reduce over 16 cs-lanes
      a0 += __shfl_xor(a0, d);
      a1 += __shfl_xor(a1, d);
      a2 += __shfl_xor(a2, d);
      a3 += __shfl_xor(a3, d);
    }

    // ---- gates + state update + h store (cs==0 threads: one per h-index) ----
    if (cs == 0) {
      const float gi = sigm(a0 + bias4[0]);
      const float gf = sigm(a1 + bias4[1]);
      const float gg = tanhf(a2 + bias4[2]);
      const float go = sigm(a3 + bias4[3]);
      c_state = gf * c_state + gi * gg;
      const float h = go * tanhf(c_state);
      astoref(outp + (size_t)(t & hmask) * HDIM + b * 32 + rr, h);
    }
    __syncthreads();                                   // B3: drains h stores (vmcnt 0)
    if (tid == 0)
      __hip_atomic_store(myflag, (unsigned)(t + 1), __ATOMIC_RELAXED,
                         __HIP_MEMORY_SCOPE_AGENT);
  }
}

// ---------------- MLP head: (T,512) -> 64 -> 32 -> 16 ----------------
__global__ void __launch_bounds__(64) mlp_head_kernel(
    const float* __restrict__ S,
    const float* __restrict__ w1, const float* __restrict__ b1,
    const float* __restrict__ w2, const float* __restrict__ b2,
    const float* __restrict__ w3, const float* __restrict__ b3,
    float* __restrict__ out)
{
  const int r   = blockIdx.x;
  const int tid = threadIdx.x;
  __shared__ float hbuf[HDIM];
  __shared__ float a1[64];
  __shared__ float a2[32];

  #pragma unroll
  for (int u = 0; u < HDIM / 64; ++u)
    hbuf[u * 64 + tid] = aloadf(S + (size_t)r * HDIM + u * 64 + tid);
  __syncthreads();

  float acc = b1[tid];
  #pragma unroll 8
  for (int k = 0; k < HDIM; ++k) acc = fmaf(hbuf[k], w1[tid * HDIM + k], acc);
  a1[tid] = acc * sigm(acc);          // SiLU
  __syncthreads();

  if (tid < 32) {
    float acc2 = b2[tid];
    #pragma unroll
    for (int k = 0; k < 64; ++k) acc2 = fmaf(a1[k], w2[tid * 64 + k], acc2);
    a2[tid] = acc2 * sigm(acc2);      // SiLU
  }
  __syncthreads();

  if (tid < 16) {
    float acc3 = b3[tid];
    #pragma unroll
    for (int k = 0; k < 32; ++k) acc3 = fmaf(a2[k], w3[tid * 32 + k], acc3);
    out[(size_t)r * 16 + tid] = acc3;
  }
}

// ---------------------------------------------------------------------------
extern "C" void kernel_launch(void* const* d_in, const int* in_sizes, int n_in,
                              void* d_out, int out_size, void* d_ws, size_t ws_size,
                              hipStream_t stream)
{
  (void)in_sizes; (void)n_in; (void)out_size; (void)ws_size;

  const float* x     = (const float*)d_in[0];
  const float* eWih0 = (const float*)d_in[1];
  const float* eWhh0 = (const float*)d_in[2];
  const float* ebih0 = (const float*)d_in[3];
  const float* ebhh0 = (const float*)d_in[4];
  const float* eWih  = (const float*)d_in[5];
  const float* eWhh  = (const float*)d_in[6];
  const float* ebih  = (const float*)d_in[7];
  const float* ebhh  = (const float*)d_in[8];
  const float* dWih  = (const float*)d_in[9];
  const float* dWhh  = (const float*)d_in[10];
  const float* dbih  = (const float*)d_in[11];
  const float* dbhh  = (const float*)d_in[12];
  const float* fc1w  = (const float*)d_in[13];
  const float* fc1b  = (const float*)d_in[14];
  const float* fc2w  = (const float*)d_in[15];
  const float* fc2b  = (const float*)d_in[16];
  const float* fc3w  = (const float*)d_in[17];
  const float* fc3b  = (const float*)d_in[18];
  float* out = (float*)d_out;

  // ws layout: ring 15*64*512 f32 | sout 4096*512 f32 | flags 16KB  (~10 MB)
  Args p{};
  p.x = x;
  p.ring  = (float*)d_ws;
  p.sout  = p.ring + (size_t)15 * RING * HDIM;
  p.flags = (unsigned*)(p.sout + (size_t)T_SEQ * HDIM);

  p.Wih[0] = eWih0; p.Whh[0] = eWhh0; p.bih[0] = ebih0; p.bhh[0] = ebhh0;
  for (int l = 1; l < 8; ++l) {
    p.Wih[l] = eWih + (size_t)(l - 1) * 4 * HDIM * HDIM;
    p.Whh[l] = eWhh + (size_t)(l - 1) * 4 * HDIM * HDIM;
    p.bih[l] = ebih + (size_t)(l - 1) * 4 * HDIM;
    p.bhh[l] = ebhh + (size_t)(l - 1) * 4 * HDIM;
  }
  for (int l = 8; l < 16; ++l) {
    p.Wih[l] = dWih + (size_t)(l - 8) * 4 * HDIM * HDIM;
    p.Whh[l] = dWhh + (size_t)(l - 8) * 4 * HDIM * HDIM;
    p.bih[l] = dbih + (size_t)(l - 8) * 4 * HDIM;
    p.bhh[l] = dbhh + (size_t)(l - 8) * 4 * HDIM;
  }

  hipMemsetAsync(p.flags, 0, (size_t)NL * BPL * FPAD * sizeof(unsigned), stream);

  void* args[] = { &p };
  hipError_t e = hipLaunchCooperativeKernel((const void*)lstm16_kernel,
                                            dim3(NL * BPL), dim3(NTH), args, 0,
                                            stream);
  if (e != hipSuccess)   // 256 blocks @ 1/CU on 256 CUs: co-resident anyway
    lstm16_kernel<<<dim3(NL * BPL), dim3(NTH), 0, stream>>>(p);

  mlp_head_kernel<<<dim3(T_SEQ), dim3(64), 0, stream>>>(
      p.sout, fc1w, fc1b, fc2w, fc2b, fc3w, fc3b, out);
}